// Round 5
// baseline (604.889 us; speedup 1.0000x reference)
//
#include <hip/hip_runtime.h>
#include <hip/hip_bf16.h>
#include <stdint.h>

#define D 1024
#define F 4096
#define E 8
#define T 8192
#define SLOT_CAP 18432   // 16384 routed slots + per-expert pad to 256
#define BM 128
#define BK 32
#define EP_STRIDE 136    // gemm2 epilogue LDS row stride (shorts)
#define EP2 264          // gemm1 epilogue stride (shorts)

typedef __attribute__((ext_vector_type(8))) short bf16x8;
typedef __attribute__((ext_vector_type(4))) float f32x4;
typedef __attribute__((ext_vector_type(8))) unsigned short u16x8;

__device__ __forceinline__ unsigned short f2bf(float f) {
  unsigned u = __float_as_uint(f);
  u += 0x7fffu + ((u >> 16) & 1u);
  return (unsigned short)(u >> 16);
}
__device__ __forceinline__ float bf2f(unsigned short u) {
  return __uint_as_float(((unsigned)u) << 16);
}

// exact-GELU via A&S 7.1.26 erf approx (|err| <= 1.5e-7), branch-free.
__device__ __forceinline__ float gelu_f(float v) {
  float s = fabsf(v) * 0.70710678118654752f;
  float t = __builtin_amdgcn_rcpf(fmaf(0.3275911f, s, 1.0f));
  float p = fmaf(t, 1.061405429f, -1.453152027f);
  p = fmaf(t, p, 1.421413741f);
  p = fmaf(t, p, -0.284496736f);
  p = fmaf(t, p, 0.254829592f);
  p = p * t;
  float e = 1.0f - p * __expf(-s * s);   // erf(|s|)
  e = copysignf(e, v);
  return 0.5f * v * (1.0f + e);
}

// global -> LDS async copy, 16B per lane. LDS dest must be wave-uniform base + lane*16.
__device__ __forceinline__ void gload16(const void* g, void* l) {
  auto gp = (const __attribute__((address_space(1))) unsigned int*)(uintptr_t)g;
  auto lp = (__attribute__((address_space(3))) unsigned int*)(unsigned)(uintptr_t)l;
  __builtin_amdgcn_global_load_lds(gp, lp, 16, 0, 0);
}

// Merged prep: blocks [0,2048) = router (fp64 accumulate -> top-2 matches fp32 ref;
// emits bf16 x). Blocks [2048,18432) = fp32->bf16 cast of w1 (w2 cast hides in gemm1).
__global__ __launch_bounds__(256) void prep_kernel(const float* __restrict__ x,
                                                   const float* __restrict__ rw,
                                                   const float* __restrict__ w1,
                                                   int* __restrict__ tok_e,
                                                   float* __restrict__ tok_p,
                                                   unsigned short* __restrict__ xg,
                                                   unsigned short* __restrict__ w1g) {
  if (blockIdx.x >= 2048) {
    int i = (blockIdx.x - 2048) * 256 + threadIdx.x;   // [0, E*F*D/8)
    const float4* p = (const float4*)w1 + (size_t)i * 2;
    float4 a = p[0], b = p[1];
    u16x8 o;
    o[0] = f2bf(a.x); o[1] = f2bf(a.y); o[2] = f2bf(a.z); o[3] = f2bf(a.w);
    o[4] = f2bf(b.x); o[5] = f2bf(b.y); o[6] = f2bf(b.z); o[7] = f2bf(b.w);
    *(u16x8*)(w1g + (size_t)i * 8) = o;
    return;
  }
  int t = blockIdx.x * 4 + (threadIdx.x >> 6);
  int lane = threadIdx.x & 63;
  const float* xp = x + (size_t)t * D;
  unsigned short* xgp = xg + (size_t)t * D;
  double acc[E];
#pragma unroll
  for (int e = 0; e < E; e++) acc[e] = 0.0;
  for (int j = 0; j < D / 64; j++) {
    float xv = xp[j * 64 + lane];
    xgp[j * 64 + lane] = f2bf(xv);
#pragma unroll
    for (int e = 0; e < E; e++) acc[e] += (double)xv * (double)rw[e * D + j * 64 + lane];
  }
#pragma unroll
  for (int e = 0; e < E; e++) {
#pragma unroll
    for (int off = 32; off >= 1; off >>= 1) acc[e] += __shfl_xor(acc[e], off, 64);
  }
  if (lane == 0) {
    double v0 = -1e300, v1 = -1e300;
    int i0 = 0, i1 = 0;
#pragma unroll
    for (int e = 0; e < E; e++) {
      double v = acc[e];
      if (v > v0) { v1 = v0; i1 = i0; v0 = v; i0 = e; }
      else if (v > v1) { v1 = v; i1 = e; }
    }
    double e1 = exp(v1 - v0);
    double s = 1.0 + e1;
    tok_e[2 * t] = i0; tok_e[2 * t + 1] = i1;
    tok_p[2 * t] = (float)(1.0 / s);
    tok_p[2 * t + 1] = (float)(e1 / s);
  }
}

// Atomic-free bucketing; pad granularity 256 (gemm1 256-row tiles; gemm2's 128 divides it).
__global__ __launch_bounds__(64) void bucket_kernel(const int* __restrict__ tok_e,
                                                    int* __restrict__ perm,
                                                    int* __restrict__ slot_of,
                                                    int* __restrict__ counts,
                                                    int* __restrict__ offp) {
  const int e = blockIdx.x;
  const int lane = threadIdx.x;
  int cnt[E];
#pragma unroll
  for (int ee = 0; ee < E; ee++) cnt[ee] = 0;
  for (int idx = lane; idx < 2 * T; idx += 64) {
    int v = tok_e[idx];
#pragma unroll
    for (int ee = 0; ee < E; ee++) cnt[ee] += (v == ee) ? 1 : 0;
  }
#pragma unroll
  for (int ee = 0; ee < E; ee++) {
#pragma unroll
    for (int off = 32; off >= 1; off >>= 1) cnt[ee] += __shfl_xor(cnt[ee], off, 64);
  }
  int off_e[E + 1];
  int o = 0;
#pragma unroll
  for (int ee = 0; ee < E; ee++) { off_e[ee] = o; o += (cnt[ee] + 255) & ~255; }
  off_e[E] = o;
  if (e == 0 && lane == 0) {
#pragma unroll
    for (int ee = 0; ee < E; ee++) { counts[ee] = cnt[ee]; offp[ee] = off_e[ee]; }
    offp[E] = o;
  }
  int base = 0, mycnt = 0, myend = 0;
#pragma unroll
  for (int ee = 0; ee < E; ee++) {
    if (ee == e) { base = off_e[ee]; mycnt = cnt[ee]; myend = off_e[ee + 1]; }
  }
  const int pad0 = base + mycnt;
  for (int r = 0; r < 2 * T / 64; r++) {
    int idx = r * 64 + lane;
    int v = tok_e[idx];
    bool m = (v == e);
    unsigned long long mask = __ballot(m);
    int pre = __popcll(mask & ((1ull << lane) - 1ull));
    if (m) {
      int slot = base + pre;
      perm[slot] = idx >> 1;
      slot_of[idx] = slot;
    }
    base += __popcll(mask);
  }
  for (int i = pad0 + lane; i < myend; i += 64) perm[i] = 0;
}

// GEMM1, m201-faithful 8-phase: 256x256 tile, 512 thr / 8 waves (2M x 4N, wave-tile
// 128x64), BK=64, 2 K-tiles per iteration, LDS 128 KiB = 2 bufs x (A 32K + B 32K).
// Per phase: {ds-read subtile (4-12 b128), stage 1 half-tile (2 gloads), barrier,
// lgkmcnt(0), setprio1, 16 MFMA, setprio0, barrier}; vmcnt(2) only at phases 4/8.
// Stage ledger (derived, all write-after-read safe via phase barriers):
//   P1:b1.A1@k1  P2:b1.B0@k1  P3:b1.B1@k1  P4:b0.A0@k0'  P5:b0.A1  P6:b0.B0
//   P7:b0.B1  P8:b1.A0@k1'   waits: P4 vmcnt(2)->buf1 landed; P8 vmcnt(2)->buf0' landed.
// MFMA quadrants (m-major, caps operand liveness ~64 VGPR):
//   P1:(m0-3,n0-1) rd aL+bA | P2:(m0-3,n2-3) rd bB | P3:(m4-7,n2-3) rd aH | P4:(m4-7,n0-1) rd bA'
// Swizzle: phys 16B-chunk = cc ^ (row&7) (row&7==fr&7 for all frags) -> uniform
// 8 lanes/slot = conflict-free (R4-verified criterion); stage pre-swizzles the
// global source within each 128B row-run -> coalesced; LDS dest linear.
// w2 cast: in-block stride-loop tail after compute (no extra LDS-reserving blocks).
__global__ __launch_bounds__(512, 2) void gemm1_kernel(const unsigned short* __restrict__ xg,
                                                       const unsigned short* __restrict__ w1g,
                                                       const float* __restrict__ b1,
                                                       const int* __restrict__ perm,
                                                       const int* __restrict__ offp,
                                                       const int* __restrict__ counts,
                                                       unsigned short* __restrict__ hbuf,
                                                       const float* __restrict__ w2,
                                                       unsigned short* __restrict__ w2g) {
  const int id = blockIdx.x;                    // grid 1152 = 8 XCD x 144 (72bm x 16bn)
  const int swz = (id & 7) * 144 + (id >> 3);
  const int bm = swz >> 4, bn = swz & 15;
  const int row0 = bm * 256;
  const int t = threadIdx.x;

  __shared__ __align__(16) unsigned short smem[65536];  // 128 KiB

  bool active = (row0 < offp[E]);
  int e = 0;
  if (active) {
#pragma unroll
    for (int i = 0; i < E; i++) if (row0 >= offp[i + 1]) e = i + 1;
    if (row0 >= offp[e] + counts[e]) active = false;
  }

  if (active) {
    const int lane = t & 63, w = t >> 6;
    const int wm = w >> 2, wn = w & 3;          // wave-tile rows wm*128, cols wn*64
    const int fr = lane & 15, fq = lane >> 4;

    // ---- staging sources (pre-swizzled global, linear LDS dest) ----
    const int r0 = t >> 3;                       // 0..63
    const int c0 = (t & 7) ^ (r0 & 7);           // source 16B-chunk within 64-col row
    const unsigned short* pA[4];
    const unsigned short* pB[4];
#pragma unroll
    for (int j = 0; j < 4; j++) {
      pA[j] = xg + (size_t)perm[row0 + j * 64 + r0] * D + c0 * 8;
      pB[j] = w1g + ((size_t)e * F + (size_t)bn * 256 + j * 64 + r0) * D + c0 * 8;
    }
    auto stgA = [&](int b, int h, int k) {
      unsigned short* d = smem + b * 32768 + h * 8192 + t * 8;
      gload16(pA[2 * h] + k, d);
      gload16(pA[2 * h + 1] + k, d + 4096);
    };
    auto stgB = [&](int b, int h, int k) {
      unsigned short* d = smem + b * 32768 + 16384 + h * 8192 + t * 8;
      gload16(pB[2 * h] + k, d);
      gload16(pB[2 * h + 1] + k, d + 4096);
    };

    // ---- ds-read addressing (shorts) ----
    int rowA[8], rowB[4];
#pragma unroll
    for (int m = 0; m < 8; m++) rowA[m] = (wm * 128 + m * 16 + fr) * 64;
#pragma unroll
    for (int n = 0; n < 4; n++) rowB[n] = 16384 + (wn * 64 + n * 16 + fr) * 64;
    const int sw0 = (fq ^ (fr & 7)) * 8;
    const int sw1 = ((4 + fq) ^ (fr & 7)) * 8;

    f32x4 acc[8][4] = {};
    bf16x8 aa[4][2], b1r[2][2], b2r[2][2];

    auto rdA4 = [&](bf16x8 a4[4][2], int mb, int bo) {
#pragma unroll
      for (int m = 0; m < 4; m++) {
        a4[m][0] = *(const bf16x8*)(smem + bo + rowA[mb + m] + sw0);
        a4[m][1] = *(const bf16x8*)(smem + bo + rowA[mb + m] + sw1);
      }
    };
    auto rdB2 = [&](bf16x8 b2v[2][2], int nb, int bo) {
#pragma unroll
      for (int n = 0; n < 2; n++) {
        b2v[n][0] = *(const bf16x8*)(smem + bo + rowB[nb + n] + sw0);
        b2v[n][1] = *(const bf16x8*)(smem + bo + rowB[nb + n] + sw1);
      }
    };
    auto mm8 = [&](int mb, int nb, bf16x8 a4[4][2], bf16x8 b2v[2][2]) {
#pragma unroll
      for (int m = 0; m < 4; m++)
#pragma unroll
        for (int n = 0; n < 2; n++)
#pragma unroll
          for (int k = 0; k < 2; k++)
            acc[mb + m][nb + n] =
                __builtin_amdgcn_mfma_f32_16x16x32_bf16(a4[m][k], b2v[n][k], acc[mb + m][nb + n], 0, 0, 0);
    };

#define PH_SYNC() do { \
    __builtin_amdgcn_s_barrier(); \
    asm volatile("s_waitcnt lgkmcnt(0)" ::: "memory"); \
    __builtin_amdgcn_sched_barrier(0); } while (0)

    // ---- prologue: buf0 fully + buf1.A0; vmcnt(2) -> buf0 landed ----
    stgA(0, 0, 0); stgA(0, 1, 0); stgB(0, 0, 0); stgB(0, 1, 0);
    stgA(1, 0, 64);
    asm volatile("s_waitcnt vmcnt(2)" ::: "memory");
    __builtin_amdgcn_s_barrier();
    __builtin_amdgcn_sched_barrier(0);

#pragma unroll 1
    for (int it = 0; it < 8; ++it) {
      const int k1 = it * 128 + 64;
      const int kn0 = it * 128 + 128;
      const int kn1 = it * 128 + 192;
      const bool more = (it < 7);
      // ================= tile0 (buf0) =================
      // P1
      rdA4(aa, 0, 0); rdB2(b1r, 0, 0);
      stgA(1, 1, k1);
      asm volatile("s_waitcnt lgkmcnt(8)" ::: "memory");
      PH_SYNC();
      __builtin_amdgcn_s_setprio(1); mm8(0, 0, aa, b1r); __builtin_amdgcn_s_setprio(0);
      __builtin_amdgcn_s_barrier();
      // P2
      rdB2(b2r, 2, 0);
      stgB(1, 0, k1);
      PH_SYNC();
      __builtin_amdgcn_s_setprio(1); mm8(0, 2, aa, b2r); __builtin_amdgcn_s_setprio(0);
      __builtin_amdgcn_s_barrier();
      // P3
      rdA4(aa, 4, 0);
      stgB(1, 1, k1);
      PH_SYNC();
      __builtin_amdgcn_s_setprio(1); mm8(4, 2, aa, b2r); __builtin_amdgcn_s_setprio(0);
      __builtin_amdgcn_s_barrier();
      // P4
      rdB2(b1r, 0, 0);
      if (more) stgA(0, 0, kn0);
      PH_SYNC();
      __builtin_amdgcn_s_setprio(1); mm8(4, 0, aa, b1r); __builtin_amdgcn_s_setprio(0);
      if (more) { asm volatile("s_waitcnt vmcnt(2)" ::: "memory"); }
      else      { asm volatile("s_waitcnt vmcnt(0)" ::: "memory"); }
      __builtin_amdgcn_s_barrier();
      // ================= tile1 (buf1) =================
      // P5
      rdA4(aa, 0, 32768); rdB2(b1r, 0, 32768);
      if (more) stgA(0, 1, kn0);
      asm volatile("s_waitcnt lgkmcnt(8)" ::: "memory");
      PH_SYNC();
      __builtin_amdgcn_s_setprio(1); mm8(0, 0, aa, b1r); __builtin_amdgcn_s_setprio(0);
      __builtin_amdgcn_s_barrier();
      // P6
      rdB2(b2r, 2, 32768);
      if (more) stgB(0, 0, kn0);
      PH_SYNC();
      __builtin_amdgcn_s_setprio(1); mm8(0, 2, aa, b2r); __builtin_amdgcn_s_setprio(0);
      __builtin_amdgcn_s_barrier();
      // P7
      rdA4(aa, 4, 32768);
      if (more) stgB(0, 1, kn0);
      PH_SYNC();
      __builtin_amdgcn_s_setprio(1); mm8(4, 2, aa, b2r); __builtin_amdgcn_s_setprio(0);
      __builtin_amdgcn_s_barrier();
      // P8
      rdB2(b1r, 0, 32768);
      if (more) stgA(1, 0, kn1);
      PH_SYNC();
      __builtin_amdgcn_s_setprio(1); mm8(4, 0, aa, b1r); __builtin_amdgcn_s_setprio(0);
      if (more) { asm volatile("s_waitcnt vmcnt(2)" ::: "memory"); }
      else      { asm volatile("s_waitcnt vmcnt(0)" ::: "memory"); }
      __builtin_amdgcn_s_barrier();
    }
#undef PH_SYNC

    // ---- epilogue: bias+gelu -> bf16 LDS half-tile (EP2) -> coalesced stores ----
    float biasv[4];
#pragma unroll
    for (int n = 0; n < 4; n++) biasv[n] = b1[e * F + bn * 256 + wn * 64 + n * 16 + fr];
    __syncthreads();
#pragma unroll
    for (int p = 0; p < 2; p++) {
      if (wm == p) {
#pragma unroll
        for (int n = 0; n < 4; n++) {
          int col = wn * 64 + n * 16 + fr;
#pragma unroll
          for (int m = 0; m < 8; m++) {
#pragma unroll
            for (int j = 0; j < 4; j++) {
              int lr = m * 16 + fq * 4 + j;
              smem[lr * EP2 + col] = f2bf(gelu_f(acc[m][n][j] + biasv[n]));
            }
          }
        }
      }
      __syncthreads();
#pragma unroll
      for (int i = 0; i < 8; i++) {
        int idx = t + i * 512;            // 4096 chunks: 128 rows x 32
        int r2 = idx >> 5, c8 = (idx & 31) * 8;
        u16x8 v = *(const u16x8*)&smem[r2 * EP2 + c8];
        *(u16x8*)&hbuf[(size_t)(row0 + p * 128 + r2) * F + (size_t)bn * 256 + c8] = v;
      }
      __syncthreads();
    }
  }

  // ---- w2 fp32->bf16 cast tail (block-strided; overlaps across staggered blocks) ----
  const int total8 = E * D * F / 8;
  for (int i = id * 512 + t; i < total8; i += 1152 * 512) {
    const float4* p = (const float4*)w2 + (size_t)i * 2;
    float4 a = p[0], b = p[1];
    u16x8 o;
    o[0] = f2bf(a.x); o[1] = f2bf(a.y); o[2] = f2bf(a.z); o[3] = f2bf(a.w);
    o[4] = f2bf(b.x); o[5] = f2bf(b.y); o[6] = f2bf(b.z); o[7] = f2bf(b.w);
    *(u16x8*)(w2g + (size_t)i * 8) = o;
  }
}

// GEMM2 (K-split-2): ypart[ks][slot][d] = h[slot][ks*2048:+2048].w2[e][d][same] (+b2 if ks==0)
// 128x128 tile, dbuf, 3 blocks/CU. Grid 2304 = 8 XCD x 288 (144bm x 8bn x 2ks).
__global__ __launch_bounds__(256, 3) void gemm2_kernel(const unsigned short* __restrict__ hbuf,
                                                       const unsigned short* __restrict__ w2g,
                                                       const float* __restrict__ b2,
                                                       const int* __restrict__ offp,
                                                       const int* __restrict__ counts,
                                                       unsigned short* __restrict__ ypart) {
  const int id = blockIdx.x;
  const int swz = (id & 7) * 288 + (id >> 3);   // bijective (2304=8*288)
  const int bn = swz & 7;                        // bn fastest -> share A panel
  const int ks = (swz >> 3) & 1;
  const int bm = swz >> 4;
  const int row0 = bm * BM;
  if (row0 >= offp[E]) return;
  int e = 0;
#pragma unroll
  for (int i = 0; i < E; i++) if (row0 >= offp[i + 1]) e = i + 1;
  const int valid_end = offp[e] + counts[e];
  if (row0 >= valid_end) return;

  const int tid = threadIdx.x, lane = tid & 63, w = tid >> 6;
  __shared__ __align__(16) unsigned short smem[BM * EP_STRIDE];
  unsigned short* As0 = smem;
  unsigned short* Bs0 = smem + 8192;

  const int kbase = ks * (F / 2);
  const unsigned short* gsrc[4];
  unsigned short* ldst[4];
#pragma unroll
  for (int i = 0; i < 4; i++) {
    int ch = tid + 256 * i;
    if (ch < 512) {
      int ar = ch >> 2, ac = (ch & 3) * 8;
      gsrc[i] = hbuf + (size_t)(row0 + ar) * F + kbase + ac;
      ldst[i] = As0 + ch * 8;
    } else {
      int c = ch - 512;
      int br = c >> 2, bc = (c & 3) * 8;
      gsrc[i] = w2g + ((size_t)e * D + (size_t)bn * BM + br) * F + kbase + bc;
      ldst[i] = Bs0 + c * 8;
    }
  }
  auto stage = [&](int k0, int buf) {
#pragma unroll
    for (int i = 0; i < 4; i++) gload16(gsrc[i] + k0, ldst[i] + buf * (BM * BK));
  };

  f32x4 acc[4][4] = {};
  const int wr = (w >> 1) * 64, wc = (w & 1) * 64;
  const int fr = lane & 15, fq = lane >> 4;

  stage(0, 0);
  __syncthreads();
  int cur = 0;
  for (int k0 = 0; k0 < F / 2; k0 += BK) {
    if (k0 + BK < F / 2) stage(k0 + BK, cur ^ 1);
    bf16x8 a[4], b[4];
#pragma unroll
    for (int m = 0; m < 4; m++) a[m] = *(const bf16x8*)&As0[cur * 4096 + (wr + m * 16 + fr) * BK + fq * 8];
#pragma unroll
    for (int n = 0; n < 4; n++) b[n] = *(const bf16x8*)&Bs0[cur * 4096 + (wc + n * 16 + fr) * BK + fq * 8];
#pragma unroll
    for (int m = 0; m < 4; m++)
#pragma unroll
      for (int n = 0; n < 4; n++)
        acc[m][n] = __builtin_amdgcn_mfma_f32_16x16x32_bf16(a[m], b[n], acc[m][n], 0, 0, 0);
    __syncthreads();
    cur ^= 1;
  }

  // epilogue via LDS (full-line coalesced stores)
#pragma unroll
  for (int n = 0; n < 4; n++) {
    int cl = wc + n * 16 + fr;
    float bias = (ks == 0) ? b2[e * D + bn * BM + cl] : 0.0f;
#pragma unroll
    for (int m = 0; m < 4; m++) {
#pragma unroll
      for (int j = 0; j < 4; j++) {
        int rl = wr + m * 16 + fq * 4 + j;
        smem[rl * EP_STRIDE + cl] = f2bf(acc[m][n][j] + bias);
      }
    }
  }
  __syncthreads();
  unsigned short* ybase = ypart + (size_t)ks * SLOT_CAP * D;
#pragma unroll
  for (int i = 0; i < 8; i++) {
    int idx = tid + i * 256;
    int r2 = idx >> 4, c = (idx & 15) * 8;
    if (row0 + r2 < valid_end) {
      u16x8 v = *(const u16x8*)&smem[r2 * EP_STRIDE + c];
      *(u16x8*)&ybase[(size_t)(row0 + r2) * D + bn * BM + c] = v;
    }
  }
}

// out[t][d] = g0*(p0[s0]+p1[s0]) + g1*(p0[s1]+p1[s1])   (full overwrite -> no memset)
__global__ __launch_bounds__(256) void combine_kernel(const unsigned short* __restrict__ ypart,
                                                      const int* __restrict__ slot_of,
                                                      const float* __restrict__ tok_p,
                                                      float* __restrict__ out) {
  int i = blockIdx.x * 256 + threadIdx.x;   // indexes 8-elem groups
  int t = i >> 7;                            // D/8 = 128 groups per token
  int g8 = i & 127;
  int s0 = slot_of[2 * t], s1 = slot_of[2 * t + 1];
  float g0 = tok_p[2 * t], g1 = tok_p[2 * t + 1];
  const unsigned short* p0 = ypart;
  const unsigned short* p1 = ypart + (size_t)SLOT_CAP * D;
  u16x8 a0 = *(const u16x8*)(p0 + (size_t)s0 * D + g8 * 8);
  u16x8 b0 = *(const u16x8*)(p1 + (size_t)s0 * D + g8 * 8);
  u16x8 a1 = *(const u16x8*)(p0 + (size_t)s1 * D + g8 * 8);
  u16x8 b1 = *(const u16x8*)(p1 + (size_t)s1 * D + g8 * 8);
  float o[8];
#pragma unroll
  for (int j = 0; j < 8; j++)
    o[j] = g0 * (bf2f(a0[j]) + bf2f(b0[j])) + g1 * (bf2f(a1[j]) + bf2f(b1[j]));
  float4* op = (float4*)(out + (size_t)t * D + g8 * 8);
  op[0] = make_float4(o[0], o[1], o[2], o[3]);
  op[1] = make_float4(o[4], o[5], o[6], o[7]);
}

extern "C" void kernel_launch(void* const* d_in, const int* in_sizes, int n_in,
                              void* d_out, int out_size, void* d_ws, size_t ws_size,
                              hipStream_t stream) {
  const float* x = (const float*)d_in[0];
  const float* rw = (const float*)d_in[1];
  const float* w1 = (const float*)d_in[2];
  const float* b1 = (const float*)d_in[3];
  const float* w2 = (const float*)d_in[4];
  const float* b2 = (const float*)d_in[5];
  float* out = (float*)d_out;

  char* ws = (char*)d_ws;
  size_t off = 0;
  auto alloc = [&](size_t bytes) {
    void* p = ws + off;
    off = (off + bytes + 255) & ~(size_t)255;
    return p;
  };
  int* counts = (int*)alloc(E * 4);
  int* offp = (int*)alloc((E + 1) * 4);
  int* tok_e = (int*)alloc((size_t)T * 2 * 4);
  float* tok_p = (float*)alloc((size_t)T * 2 * 4);
  int* perm = (int*)alloc((size_t)SLOT_CAP * 4);
  int* slot_of = (int*)alloc((size_t)T * 2 * 4);
  unsigned short* xg = (unsigned short*)alloc((size_t)T * D * 2);        // 16.8 MB
  unsigned short* w1g = (unsigned short*)alloc((size_t)E * F * D * 2);   // 67 MB
  unsigned short* w2g = (unsigned short*)alloc((size_t)E * D * F * 2);   // 67 MB
  unsigned short* hbuf = (unsigned short*)alloc((size_t)SLOT_CAP * F * 2); // 151 MB
  // ypart: 2 bf16 partial buffers, 75.5 MB, aliased over xg(16.8)+w1g(67)
  // (dead after gemm1; re-written by prep every call -> deterministic).
  unsigned short* ypart = xg;
  (void)ws_size; (void)in_sizes; (void)n_in; (void)out_size;

  hipLaunchKernelGGL(prep_kernel, dim3(2048 + E * F * D / 8 / 256), dim3(256), 0, stream,
                     x, rw, w1, tok_e, tok_p, xg, w1g);
  hipLaunchKernelGGL(bucket_kernel, dim3(E), dim3(64), 0, stream,
                     tok_e, perm, slot_of, counts, offp);
  hipLaunchKernelGGL(gemm1_kernel, dim3(1152), dim3(512), 0, stream,
                     xg, w1g, b1, perm, offp, counts, hbuf, w2, w2g);
  hipLaunchKernelGGL(gemm2_kernel, dim3(2304), dim3(256), 0, stream,
                     hbuf, w2g, b2, offp, counts, ypart);
  hipLaunchKernelGGL(combine_kernel, dim3(T * D / 8 / 256), dim3(256), 0, stream,
                     ypart, slot_of, tok_p, out);
}

// Round 6
// 553.526 us; speedup vs baseline: 1.0928x; 1.0928x over previous
//
#include <hip/hip_runtime.h>
#include <hip/hip_bf16.h>
#include <stdint.h>

#define D 1024
#define F 4096
#define E 8
#define T 8192
#define SLOT_CAP 17408   // 16384 routed slots + per-expert pad to 128
#define BM 128
#define BK 32
#define EP_STRIDE 136    // epilogue LDS row stride (shorts): +8 pad kills bank conflicts

typedef __attribute__((ext_vector_type(8))) short bf16x8;
typedef __attribute__((ext_vector_type(4))) float f32x4;
typedef __attribute__((ext_vector_type(8))) unsigned short u16x8;

__device__ __forceinline__ unsigned short f2bf(float f) {
  unsigned u = __float_as_uint(f);
  u += 0x7fffu + ((u >> 16) & 1u);
  return (unsigned short)(u >> 16);
}
__device__ __forceinline__ float bf2f(unsigned short u) {
  return __uint_as_float(((unsigned)u) << 16);
}

// exact-GELU via A&S 7.1.26 erf approx (|err| <= 1.5e-7), branch-free.
__device__ __forceinline__ float gelu_f(float v) {
  float s = fabsf(v) * 0.70710678118654752f;
  float t = __builtin_amdgcn_rcpf(fmaf(0.3275911f, s, 1.0f));
  float p = fmaf(t, 1.061405429f, -1.453152027f);
  p = fmaf(t, p, 1.421413741f);
  p = fmaf(t, p, -0.284496736f);
  p = fmaf(t, p, 0.254829592f);
  p = p * t;
  float e = 1.0f - p * __expf(-s * s);   // erf(|s|)
  e = copysignf(e, v);
  return 0.5f * v * (1.0f + e);
}

// global -> LDS async copy, 16B per lane. LDS dest must be wave-uniform base + lane*16.
__device__ __forceinline__ void gload16(const void* g, void* l) {
  auto gp = (const __attribute__((address_space(1))) unsigned int*)(uintptr_t)g;
  auto lp = (__attribute__((address_space(3))) unsigned int*)(unsigned)(uintptr_t)l;
  __builtin_amdgcn_global_load_lds(gp, lp, 16, 0, 0);
}

// Merged prep: blocks [0,2048) = router (1 wave/token, fp64 accumulate so top-2
// selection matches the fp32 reference; also emits bf16 x). Blocks [2048,18432) =
// fp32->bf16 cast of w1 ONLY. The w2 cast is deferred into gemm1's launch (it is
// not needed until gemm2) so its ~200 MB of traffic hides under gemm1 compute.
__global__ __launch_bounds__(256) void prep_kernel(const float* __restrict__ x,
                                                   const float* __restrict__ rw,
                                                   const float* __restrict__ w1,
                                                   int* __restrict__ tok_e,
                                                   float* __restrict__ tok_p,
                                                   unsigned short* __restrict__ xg,
                                                   unsigned short* __restrict__ w1g) {
  if (blockIdx.x >= 2048) {
    int i = (blockIdx.x - 2048) * 256 + threadIdx.x;   // [0, E*F*D/8)
    const float4* p = (const float4*)w1 + (size_t)i * 2;
    float4 a = p[0], b = p[1];
    u16x8 o;
    o[0] = f2bf(a.x); o[1] = f2bf(a.y); o[2] = f2bf(a.z); o[3] = f2bf(a.w);
    o[4] = f2bf(b.x); o[5] = f2bf(b.y); o[6] = f2bf(b.z); o[7] = f2bf(b.w);
    *(u16x8*)(w1g + (size_t)i * 8) = o;
    return;
  }
  int t = blockIdx.x * 4 + (threadIdx.x >> 6);
  int lane = threadIdx.x & 63;
  const float* xp = x + (size_t)t * D;
  unsigned short* xgp = xg + (size_t)t * D;
  double acc[E];
#pragma unroll
  for (int e = 0; e < E; e++) acc[e] = 0.0;
  for (int j = 0; j < D / 64; j++) {
    float xv = xp[j * 64 + lane];
    xgp[j * 64 + lane] = f2bf(xv);
#pragma unroll
    for (int e = 0; e < E; e++) acc[e] += (double)xv * (double)rw[e * D + j * 64 + lane];
  }
#pragma unroll
  for (int e = 0; e < E; e++) {
#pragma unroll
    for (int off = 32; off >= 1; off >>= 1) acc[e] += __shfl_xor(acc[e], off, 64);
  }
  if (lane == 0) {
    double v0 = -1e300, v1 = -1e300;
    int i0 = 0, i1 = 0;
#pragma unroll
    for (int e = 0; e < E; e++) {
      double v = acc[e];
      if (v > v0) { v1 = v0; i1 = i0; v0 = v; i0 = e; }
      else if (v > v1) { v1 = v; i1 = e; }
    }
    double e1 = exp(v1 - v0);
    double s = 1.0 + e1;
    tok_e[2 * t] = i0; tok_e[2 * t + 1] = i1;
    tok_p[2 * t] = (float)(1.0 / s);
    tok_p[2 * t + 1] = (float)(e1 / s);
  }
}

// Atomic-free bucketing: 8 blocks x 1 wave. Block e computes the full histogram
// (shfl-reduced), derives offp locally, then rank-scatters its expert's entries via
// ballot+popc (deterministic), zeroes its pad region. Block 0 publishes counts/offp.
__global__ __launch_bounds__(64) void bucket_kernel(const int* __restrict__ tok_e,
                                                    int* __restrict__ perm,
                                                    int* __restrict__ slot_of,
                                                    int* __restrict__ counts,
                                                    int* __restrict__ offp) {
  const int e = blockIdx.x;
  const int lane = threadIdx.x;
  int cnt[E];
#pragma unroll
  for (int ee = 0; ee < E; ee++) cnt[ee] = 0;
  for (int idx = lane; idx < 2 * T; idx += 64) {
    int v = tok_e[idx];
#pragma unroll
    for (int ee = 0; ee < E; ee++) cnt[ee] += (v == ee) ? 1 : 0;
  }
#pragma unroll
  for (int ee = 0; ee < E; ee++) {
#pragma unroll
    for (int off = 32; off >= 1; off >>= 1) cnt[ee] += __shfl_xor(cnt[ee], off, 64);
  }
  int off_e[E + 1];
  int o = 0;
#pragma unroll
  for (int ee = 0; ee < E; ee++) { off_e[ee] = o; o += (cnt[ee] + (BM - 1)) & ~(BM - 1); }
  off_e[E] = o;
  if (e == 0 && lane == 0) {
#pragma unroll
    for (int ee = 0; ee < E; ee++) { counts[ee] = cnt[ee]; offp[ee] = off_e[ee]; }
    offp[E] = o;
  }
  int base = 0, mycnt = 0, myend = 0;
#pragma unroll
  for (int ee = 0; ee < E; ee++) {
    if (ee == e) { base = off_e[ee]; mycnt = cnt[ee]; myend = off_e[ee + 1]; }
  }
  const int pad0 = base + mycnt;
  for (int r = 0; r < 2 * T / 64; r++) {
    int idx = r * 64 + lane;
    int v = tok_e[idx];
    bool m = (v == e);
    unsigned long long mask = __ballot(m);
    int pre = __popcll(mask & ((1ull << lane) - 1ull));
    if (m) {
      int slot = base + pre;
      perm[slot] = idx >> 1;
      slot_of[idx] = slot;
    }
    base += __popcll(mask);
  }
  for (int i = pad0 + lane; i < myend; i += 64) perm[i] = 0;
}

// GEMM1: hbuf[slot][f] = gelu( x[perm[slot]] . w1[e][f] + b1[e][f] ), bf16 out
// 128x128 tile, dbuf, 4 blocks/CU (R6: launch_bounds(256,4) — allocator must fit
// <=128 total regs; R3 used 72 arch + 64 acc = 136 -> 3 waves/SIMD was the limiter,
// not LDS. 4th co-resident block converts 2-phase barrier stalls into MFMA issue).
// XCD-chunked (8 x 544) quarter-walk. Blocks [4352, 20736): fp32->bf16 cast of w2
// (backfills free CU slots while compute blocks run).
__global__ __launch_bounds__(256, 4) void gemm1_kernel(const unsigned short* __restrict__ xg,
                                                       const unsigned short* __restrict__ w1g,
                                                       const float* __restrict__ b1,
                                                       const int* __restrict__ perm,
                                                       const int* __restrict__ offp,
                                                       const int* __restrict__ counts,
                                                       unsigned short* __restrict__ hbuf,
                                                       const float* __restrict__ w2,
                                                       unsigned short* __restrict__ w2g) {
  const int id = blockIdx.x;
  if (id >= 4352) {                              // trailing w2-cast blocks
    int i = (id - 4352) * 256 + threadIdx.x;     // [0, E*D*F/8)
    const float4* p = (const float4*)w2 + (size_t)i * 2;
    float4 a = p[0], b = p[1];
    u16x8 o;
    o[0] = f2bf(a.x); o[1] = f2bf(a.y); o[2] = f2bf(a.z); o[3] = f2bf(a.w);
    o[4] = f2bf(b.x); o[5] = f2bf(b.y); o[6] = f2bf(b.z); o[7] = f2bf(b.w);
    *(u16x8*)(w2g + (size_t)i * 8) = o;
    return;
  }
  const int xcd = id & 7, loc = id >> 3;        // loc in [0,544)
  const int q = loc / 136, r = loc % 136;       // 4 quarters x (17bm x 8bn)
  const int bm = xcd * 17 + (r >> 3);
  const int bn = q * 8 + (r & 7);
  const int row0 = bm * BM;
  if (row0 >= offp[E]) return;
  int e = 0;
#pragma unroll
  for (int i = 0; i < E; i++) if (row0 >= offp[i + 1]) e = i + 1;
  if (row0 >= offp[e] + counts[e]) return;  // block entirely padding

  const int tid = threadIdx.x, lane = tid & 63, w = tid >> 6;
  __shared__ __align__(16) unsigned short smem[BM * EP_STRIDE];
  unsigned short* As0 = smem;            // As[buf] = As0 + buf*4096
  unsigned short* Bs0 = smem + 8192;     // Bs[buf] = Bs0 + buf*4096

  const unsigned short* gsrc[4];
  unsigned short* ldst[4];
#pragma unroll
  for (int i = 0; i < 4; i++) {
    int ch = tid + 256 * i;
    if (ch < 512) {
      int ar = ch >> 2, ac = (ch & 3) * 8;
      gsrc[i] = xg + (size_t)perm[row0 + ar] * D + ac;
      ldst[i] = As0 + ch * 8;
    } else {
      int c = ch - 512;
      int br = c >> 2, bc = (c & 3) * 8;
      gsrc[i] = w1g + ((size_t)e * F + (size_t)bn * BM + br) * D + bc;
      ldst[i] = Bs0 + c * 8;
    }
  }
  auto stage = [&](int k0, int buf) {
#pragma unroll
    for (int i = 0; i < 4; i++) gload16(gsrc[i] + k0, ldst[i] + buf * (BM * BK));
  };

  f32x4 acc[4][4] = {};
  const int wr = (w >> 1) * 64, wc = (w & 1) * 64;
  const int fr = lane & 15, fq = lane >> 4;

  stage(0, 0);
  __syncthreads();
  int cur = 0;
  for (int k0 = 0; k0 < D; k0 += BK) {
    if (k0 + BK < D) stage(k0 + BK, cur ^ 1);   // prefetch flies during compute
    bf16x8 a[4], b[4];
#pragma unroll
    for (int m = 0; m < 4; m++) a[m] = *(const bf16x8*)&As0[cur * 4096 + (wr + m * 16 + fr) * BK + fq * 8];
#pragma unroll
    for (int n = 0; n < 4; n++) b[n] = *(const bf16x8*)&Bs0[cur * 4096 + (wc + n * 16 + fr) * BK + fq * 8];
#pragma unroll
    for (int m = 0; m < 4; m++)
#pragma unroll
      for (int n = 0; n < 4; n++)
        acc[m][n] = __builtin_amdgcn_mfma_f32_16x16x32_bf16(a[m], b[n], acc[m][n], 0, 0, 0);
    __syncthreads();
    cur ^= 1;
  }

  // epilogue: bias+gelu in-register -> bf16 LDS tile -> coalesced 16B/lane stores
#pragma unroll
  for (int n = 0; n < 4; n++) {
    int cl = wc + n * 16 + fr;
    float bias = b1[e * F + bn * BM + cl];
#pragma unroll
    for (int m = 0; m < 4; m++) {
#pragma unroll
      for (int j = 0; j < 4; j++) {
        int rl = wr + m * 16 + fq * 4 + j;
        smem[rl * EP_STRIDE + cl] = f2bf(gelu_f(acc[m][n][j] + bias));
      }
    }
  }
  __syncthreads();
#pragma unroll
  for (int i = 0; i < 8; i++) {
    int idx = tid + i * 256;          // 2048 16B-chunks: 128 rows x 16
    int r2 = idx >> 4, c = (idx & 15) * 8;
    u16x8 v = *(const u16x8*)&smem[r2 * EP_STRIDE + c];
    *(u16x8*)&hbuf[(size_t)(row0 + r2) * F + bn * BM + c] = v;
  }
}

// GEMM2 (K-split-2): ypart[ks][slot][d] = h[slot][ks*2048:+2048].w2[e][d][same] (+b2 if ks==0)
// 128x128 tile, dbuf, 4 blocks/CU (R6). Grid 2176 = 8bn x 2ks x 136bm = 8*272.
__global__ __launch_bounds__(256, 4) void gemm2_kernel(const unsigned short* __restrict__ hbuf,
                                                       const unsigned short* __restrict__ w2g,
                                                       const float* __restrict__ b2,
                                                       const int* __restrict__ offp,
                                                       const int* __restrict__ counts,
                                                       unsigned short* __restrict__ ypart) {
  const int id = blockIdx.x;
  const int swz = (id & 7) * 272 + (id >> 3);   // bijective (2176=8*272)
  const int bn = swz & 7;                        // bn fastest -> share A panel
  const int ks = (swz >> 3) & 1;
  const int bm = swz >> 4;
  const int row0 = bm * BM;
  if (row0 >= offp[E]) return;
  int e = 0;
#pragma unroll
  for (int i = 0; i < E; i++) if (row0 >= offp[i + 1]) e = i + 1;
  const int valid_end = offp[e] + counts[e];
  if (row0 >= valid_end) return;

  const int tid = threadIdx.x, lane = tid & 63, w = tid >> 6;
  __shared__ __align__(16) unsigned short smem[BM * EP_STRIDE];
  unsigned short* As0 = smem;
  unsigned short* Bs0 = smem + 8192;

  const int kbase = ks * (F / 2);
  const unsigned short* gsrc[4];
  unsigned short* ldst[4];
#pragma unroll
  for (int i = 0; i < 4; i++) {
    int ch = tid + 256 * i;
    if (ch < 512) {
      int ar = ch >> 2, ac = (ch & 3) * 8;
      gsrc[i] = hbuf + (size_t)(row0 + ar) * F + kbase + ac;
      ldst[i] = As0 + ch * 8;
    } else {
      int c = ch - 512;
      int br = c >> 2, bc = (c & 3) * 8;
      gsrc[i] = w2g + ((size_t)e * D + (size_t)bn * BM + br) * F + kbase + bc;
      ldst[i] = Bs0 + c * 8;
    }
  }
  auto stage = [&](int k0, int buf) {
#pragma unroll
    for (int i = 0; i < 4; i++) gload16(gsrc[i] + k0, ldst[i] + buf * (BM * BK));
  };

  f32x4 acc[4][4] = {};
  const int wr = (w >> 1) * 64, wc = (w & 1) * 64;
  const int fr = lane & 15, fq = lane >> 4;

  stage(0, 0);
  __syncthreads();
  int cur = 0;
  for (int k0 = 0; k0 < F / 2; k0 += BK) {
    if (k0 + BK < F / 2) stage(k0 + BK, cur ^ 1);
    bf16x8 a[4], b[4];
#pragma unroll
    for (int m = 0; m < 4; m++) a[m] = *(const bf16x8*)&As0[cur * 4096 + (wr + m * 16 + fr) * BK + fq * 8];
#pragma unroll
    for (int n = 0; n < 4; n++) b[n] = *(const bf16x8*)&Bs0[cur * 4096 + (wc + n * 16 + fr) * BK + fq * 8];
#pragma unroll
    for (int m = 0; m < 4; m++)
#pragma unroll
      for (int n = 0; n < 4; n++)
        acc[m][n] = __builtin_amdgcn_mfma_f32_16x16x32_bf16(a[m], b[n], acc[m][n], 0, 0, 0);
    __syncthreads();
    cur ^= 1;
  }

  // epilogue via LDS (full-line coalesced stores)
#pragma unroll
  for (int n = 0; n < 4; n++) {
    int cl = wc + n * 16 + fr;
    float bias = (ks == 0) ? b2[e * D + bn * BM + cl] : 0.0f;
#pragma unroll
    for (int m = 0; m < 4; m++) {
#pragma unroll
      for (int j = 0; j < 4; j++) {
        int rl = wr + m * 16 + fq * 4 + j;
        smem[rl * EP_STRIDE + cl] = f2bf(acc[m][n][j] + bias);
      }
    }
  }
  __syncthreads();
  unsigned short* ybase = ypart + (size_t)ks * SLOT_CAP * D;
#pragma unroll
  for (int i = 0; i < 8; i++) {
    int idx = tid + i * 256;
    int r2 = idx >> 4, c = (idx & 15) * 8;
    if (row0 + r2 < valid_end) {
      u16x8 v = *(const u16x8*)&smem[r2 * EP_STRIDE + c];
      *(u16x8*)&ybase[(size_t)(row0 + r2) * D + bn * BM + c] = v;
    }
  }
}

// out[t][d] = g0*(p0[s0]+p1[s0]) + g1*(p0[s1]+p1[s1])   (full overwrite -> no memset)
__global__ __launch_bounds__(256) void combine_kernel(const unsigned short* __restrict__ ypart,
                                                      const int* __restrict__ slot_of,
                                                      const float* __restrict__ tok_p,
                                                      float* __restrict__ out) {
  int i = blockIdx.x * 256 + threadIdx.x;   // indexes 8-elem groups
  int t = i >> 7;                            // D/8 = 128 groups per token
  int g8 = i & 127;
  int s0 = slot_of[2 * t], s1 = slot_of[2 * t + 1];
  float g0 = tok_p[2 * t], g1 = tok_p[2 * t + 1];
  const unsigned short* p0 = ypart;
  const unsigned short* p1 = ypart + (size_t)SLOT_CAP * D;
  u16x8 a0 = *(const u16x8*)(p0 + (size_t)s0 * D + g8 * 8);
  u16x8 b0 = *(const u16x8*)(p1 + (size_t)s0 * D + g8 * 8);
  u16x8 a1 = *(const u16x8*)(p0 + (size_t)s1 * D + g8 * 8);
  u16x8 b1 = *(const u16x8*)(p1 + (size_t)s1 * D + g8 * 8);
  float o[8];
#pragma unroll
  for (int j = 0; j < 8; j++)
    o[j] = g0 * (bf2f(a0[j]) + bf2f(b0[j])) + g1 * (bf2f(a1[j]) + bf2f(b1[j]));
  float4* op = (float4*)(out + (size_t)t * D + g8 * 8);
  op[0] = make_float4(o[0], o[1], o[2], o[3]);
  op[1] = make_float4(o[4], o[5], o[6], o[7]);
}

extern "C" void kernel_launch(void* const* d_in, const int* in_sizes, int n_in,
                              void* d_out, int out_size, void* d_ws, size_t ws_size,
                              hipStream_t stream) {
  const float* x = (const float*)d_in[0];
  const float* rw = (const float*)d_in[1];
  const float* w1 = (const float*)d_in[2];
  const float* b1 = (const float*)d_in[3];
  const float* w2 = (const float*)d_in[4];
  const float* b2 = (const float*)d_in[5];
  float* out = (float*)d_out;

  char* ws = (char*)d_ws;
  size_t off = 0;
  auto alloc = [&](size_t bytes) {
    void* p = ws + off;
    off = (off + bytes + 255) & ~(size_t)255;
    return p;
  };
  int* counts = (int*)alloc(E * 4);
  int* offp = (int*)alloc((E + 1) * 4);
  int* tok_e = (int*)alloc((size_t)T * 2 * 4);
  float* tok_p = (float*)alloc((size_t)T * 2 * 4);
  int* perm = (int*)alloc((size_t)SLOT_CAP * 4);
  int* slot_of = (int*)alloc((size_t)T * 2 * 4);
  unsigned short* xg = (unsigned short*)alloc((size_t)T * D * 2);        // 16.8 MB
  unsigned short* w1g = (unsigned short*)alloc((size_t)E * F * D * 2);   // 67 MB
  unsigned short* w2g = (unsigned short*)alloc((size_t)E * D * F * 2);   // 67 MB
  unsigned short* hbuf = (unsigned short*)alloc((size_t)SLOT_CAP * F * 2); // 143 MB
  // ypart: 2 bf16 partial buffers, 71.3 MB, aliased over xg(16.8)+w1g(67)
  // (dead after gemm1; re-written by prep every call -> deterministic).
  unsigned short* ypart = xg;
  (void)ws_size; (void)in_sizes; (void)n_in; (void)out_size;

  hipLaunchKernelGGL(prep_kernel, dim3(2048 + E * F * D / 8 / 256), dim3(256), 0, stream,
                     x, rw, w1, tok_e, tok_p, xg, w1g);
  hipLaunchKernelGGL(bucket_kernel, dim3(E), dim3(64), 0, stream,
                     tok_e, perm, slot_of, counts, offp);
  hipLaunchKernelGGL(gemm1_kernel, dim3(4352 + E * D * F / 8 / 256), dim3(256), 0, stream,
                     xg, w1g, b1, perm, offp, counts, hbuf, w2, w2g);
  hipLaunchKernelGGL(gemm2_kernel, dim3(2176), dim3(256), 0, stream,
                     hbuf, w2g, b2, offp, counts, ypart);
  hipLaunchKernelGGL(combine_kernel, dim3(T * D / 8 / 256), dim3(256), 0, stream,
                     ypart, slot_of, tok_p, out);
}